// Round 4
// baseline (234.611 us; speedup 1.0000x reference)
//
#include <hip/hip_runtime.h>
#include <stdint.h>

// Problem constants (from reference)
#define BB 16
#define HH 299
#define WW 299
#define KK 8
#define HWPIX (HH * WW)        // 89401
#define NPIX (BB * HWPIX)      // 1430416
#define PPT 2                  // pixels per thread (MLP: 16 gathers in flight)
#define TPB 256
#define SPAN (TPB * PPT)

typedef float f4 __attribute__((ext_vector_type(4)));
typedef unsigned int v4u __attribute__((ext_vector_type(4)));

// Gather with sc0 (L1 bypass, L2 cached): 16B request served from L2 directly,
// no 64B line fill, no L1 MSHR occupancy. Compiler tracks the dependency.
static __device__ __forceinline__ f4 gather_sc0(__amdgpu_buffer_rsrc_t srd, int idx) {
    v4u r = __builtin_amdgcn_raw_buffer_load_b128(srd, idx * 16, 0, /*aux=sc0*/1);
    return __builtin_bit_cast(f4, r);
}

__global__ __launch_bounds__(TPB) void gauss_net_kernel(
    const f4* __restrict__ spatial,  // (N_POINTS, 4)
    const f4* __restrict__ wi4,      // (B, 2, H, W, K) viewed as f4
    const f4* __restrict__ ori,      // (B, H, W, 4)
    float* __restrict__ out)
{
    const int tbase = blockIdx.x * SPAN + threadIdx.x;

    // Buffer resource for the spatial table: raw (stride=0), bounds disabled.
    __amdgpu_buffer_rsrc_t srd = __builtin_amdgcn_make_buffer_rsrc(
        (void*)spatial, /*stride=*/0, /*num_records=*/0xFFFFFFFFu,
        /*flags=*/0x00020000u);

    // Output layout (flat float offsets)
    f4*    out_x    = (f4*)out;
    f4*    out_rgba = out_x + NPIX;
    float* out_cla  = (float*)(out_rgba + NPIX);
    f4*    out_ori  = (f4*)(out_cla + (size_t)BB * 3 * HWPIX);
    float* out_ocla = (float*)(out_ori + NPIX);

    int  p[PPT], bidx[PPT], rem[PPT];
    bool act[PPT];
    f4   w0[PPT], w1[PPT], i0[PPT], i1[PPT], o[PPT];

    // Phase 1: issue ALL streaming loads (weights, indices, ori) — nt, read-once
#pragma unroll
    for (int u = 0; u < PPT; ++u) {
        p[u]   = tbase + u * TPB;
        act[u] = (p[u] < NPIX);
        int pc = act[u] ? p[u] : 0;
        bidx[u] = pc / HWPIX;
        rem[u]  = pc - bidx[u] * HWPIX;
        size_t wb = ((size_t)(2 * bidx[u]) * HWPIX + rem[u]) * 2;  // f4 units
        size_t ib = wb + (size_t)HWPIX * 2;
        w0[u] = __builtin_nontemporal_load(wi4 + wb);
        w1[u] = __builtin_nontemporal_load(wi4 + wb + 1);
        i0[u] = __builtin_nontemporal_load(wi4 + ib);
        i1[u] = __builtin_nontemporal_load(wi4 + ib + 1);
        o[u]  = __builtin_nontemporal_load(ori + pc);
    }

    // Phase 2: issue ALL gathers (sc0, L2-direct) before consuming any.
    f4 g[PPT][KK];
#pragma unroll
    for (int u = 0; u < PPT; ++u) {
        int id[KK] = { (int)i0[u].x, (int)i0[u].y, (int)i0[u].z, (int)i0[u].w,
                       (int)i1[u].x, (int)i1[u].y, (int)i1[u].z, (int)i1[u].w };
#pragma unroll
        for (int k = 0; k < KK; ++k) g[u][k] = gather_sc0(srd, id[k]);
    }

    // Phase 3: reduce + epilogue + nt stores
#pragma unroll
    for (int u = 0; u < PPT; ++u) {
        if (!act[u]) continue;
        float wt[KK] = { w0[u].x, w0[u].y, w0[u].z, w0[u].w,
                         w1[u].x, w1[u].y, w1[u].z, w1[u].w };
        f4 acc = (f4){0.f, 0.f, 0.f, 0.f};
#pragma unroll
        for (int k = 0; k < KK; ++k) acc += g[u][k] * wt[k];

        f4 ov = o[u];
        float alpha = acc.w * (1.0f / 255.0f);
        float r  = fmaf(acc.x, alpha, ov.x);
        float gr = fmaf(acc.y, alpha, ov.y);
        float bl = fmaf(acc.z, alpha, ov.z);
        bool oa_pos = (ov.w > 0.0f);
        if (!oa_pos) { r = 0.f; gr = 0.f; bl = 0.f; }

        float cr = fminf(fmaxf(r,  0.f), 255.f);
        float cg = fminf(fmaxf(gr, 0.f), 255.f);
        float cb = fminf(fmaxf(bl, 0.f), 255.f);
        float ca = fminf(fmaxf(ov.w, 0.f), 255.f);

        __builtin_nontemporal_store(acc, out_x + p[u]);
        __builtin_nontemporal_store((f4){cr, cg, cb, ca}, out_rgba + p[u]);
        __builtin_nontemporal_store(ov, out_ori + p[u]);

        size_t cbase = (size_t)bidx[u] * 3 * HWPIX + rem[u];
        bool ca_pos = (ca > 0.0f);
        __builtin_nontemporal_store(ca_pos ? cr : 255.0f, out_cla + cbase);
        __builtin_nontemporal_store(ca_pos ? cg : 255.0f, out_cla + cbase + HWPIX);
        __builtin_nontemporal_store(ca_pos ? cb : 255.0f, out_cla + cbase + 2 * HWPIX);

        __builtin_nontemporal_store(oa_pos ? ov.x : 255.0f, out_ocla + cbase);
        __builtin_nontemporal_store(oa_pos ? ov.y : 255.0f, out_ocla + cbase + HWPIX);
        __builtin_nontemporal_store(oa_pos ? ov.z : 255.0f, out_ocla + cbase + 2 * HWPIX);
    }
}

extern "C" void kernel_launch(void* const* d_in, const int* in_sizes, int n_in,
                              void* d_out, int out_size, void* d_ws, size_t ws_size,
                              hipStream_t stream) {
    const f4* spatial = (const f4*)d_in[0];
    const f4* wi4     = (const f4*)d_in[1];
    const f4* ori     = (const f4*)d_in[2];
    float* out = (float*)d_out;

    int blocks = (NPIX + SPAN - 1) / SPAN;
    gauss_net_kernel<<<blocks, TPB, 0, stream>>>(spatial, wi4, ori, out);
}